// Round 1
// baseline (385.460 us; speedup 1.0000x reference)
//
#include <hip/hip_runtime.h>
#include <math.h>

#define DIM 4096
#define NQ 12
#define BATCH 128

// ---------------------------------------------------------------------------
// Kernel 1: X = GELU(inputs @ W_pre^T + b_pre)
// inputs: 128 x 4096 (row-major), W_pre: 4096 x 4096 (row-major)
// x[b][j] = sum_k inputs[b][k] * W_pre[j][k] + b_pre[j]  (both stream along k)
// Tile: BM=64 (batch) x BN=64 (out), BK=16. 256 threads, 4x4 acc each.
// ---------------------------------------------------------------------------
__global__ __launch_bounds__(256) void gemm_gelu_kernel(
    const float* __restrict__ A, const float* __restrict__ W,
    const float* __restrict__ bias, float* __restrict__ X)
{
    __shared__ float As[16][64 + 4];   // [k][m], pad keeps float4 16B-aligned & banks spread
    __shared__ float Bs[16][64 + 4];   // [k][n]
    const int t  = threadIdx.x;
    const int bm = blockIdx.y * 64;
    const int bn = blockIdx.x * 64;
    const int tn = (t & 15) * 4;       // output col group
    const int tm = (t >> 4) * 4;       // output row group
    const int lr = t >> 2;             // staging row 0..63
    const int lk = (t & 3) * 4;        // staging k-offset 0,4,8,12

    float acc[4][4] = {};
    const float* aptr = A + (size_t)(bm + lr) * DIM + lk;
    const float* bptr = W + (size_t)(bn + lr) * DIM + lk;

    for (int k0 = 0; k0 < DIM; k0 += 16) {
        float4 a4 = *(const float4*)(aptr + k0);
        float4 b4 = *(const float4*)(bptr + k0);
        __syncthreads();   // previous iteration's reads done
        As[lk + 0][lr] = a4.x; As[lk + 1][lr] = a4.y;
        As[lk + 2][lr] = a4.z; As[lk + 3][lr] = a4.w;
        Bs[lk + 0][lr] = b4.x; Bs[lk + 1][lr] = b4.y;
        Bs[lk + 2][lr] = b4.z; Bs[lk + 3][lr] = b4.w;
        __syncthreads();
#pragma unroll
        for (int k = 0; k < 16; ++k) {
            float4 av = *(const float4*)&As[k][tm];
            float4 bv = *(const float4*)&Bs[k][tn];
            float am[4] = {av.x, av.y, av.z, av.w};
            float bb[4] = {bv.x, bv.y, bv.z, bv.w};
#pragma unroll
            for (int i = 0; i < 4; ++i)
#pragma unroll
                for (int j = 0; j < 4; ++j)
                    acc[i][j] = fmaf(am[i], bb[j], acc[i][j]);
        }
    }

#pragma unroll
    for (int i = 0; i < 4; ++i) {
        const int m = bm + tm + i;
#pragma unroll
        for (int j = 0; j < 4; ++j) {
            const int n = bn + tn + j;
            float h = acc[i][j] + bias[n];
            // exact GELU: 0.5*h*(1+erf(h/sqrt(2)))
            X[(size_t)m * DIM + n] = 0.5f * h * (1.0f + erff(h * 0.70710678118654752f));
        }
    }
}

// ---------------------------------------------------------------------------
// Kernel 2: per-batch-item quantum circuit, state in LDS.
// wire q <-> bit position (11-q) (wire 0 = MSB, PennyLane convention).
// 4 reps x 4 layers: 12 Rot gates (one barrier each) + all-12-CNOT permutation
// folded into a single gather pass (CNOT network is GF(2)-linear).
// ---------------------------------------------------------------------------
__global__ __launch_bounds__(256) void circuit_kernel(
    const float* __restrict__ X, const float* __restrict__ qw,
    const float* __restrict__ Wfc, const float* __restrict__ bfc,
    float* __restrict__ out)
{
    __shared__ float re[DIM];
    __shared__ float im[DIM];
    __shared__ float gm[48][8];      // 4 layers x 12 qubits: u00,u01,u10,u11 (re,im)
    __shared__ float redbuf[4 * NQ];
    __shared__ float zs[NQ];
    __shared__ float snorm[4];

    const int t = threadIdx.x;
    const int b = blockIdx.x;
    const int wave = t >> 6;

    // ---- load GELU'd row, compute norm ----
    float x[16];
    float ss = 0.f;
#pragma unroll
    for (int j = 0; j < 16; ++j) {
        x[j] = X[(size_t)b * DIM + t + j * 256];
        ss = fmaf(x[j], x[j], ss);
    }
#pragma unroll
    for (int off = 32; off; off >>= 1) ss += __shfl_xor(ss, off);
    if ((t & 63) == 0) snorm[wave] = ss;

    // ---- gate matrices (48 of them), one thread each ----
    if (t < 48) {
        const int base = t * 3;
        const float phi = qw[base + 0], th = qw[base + 1], om = qw[base + 2];
        float c, s, chp, shp, chm, shm;
        sincosf(0.5f * th, &s, &c);
        sincosf(0.5f * (phi + om), &shp, &chp);
        sincosf(0.5f * (phi - om), &shm, &chm);
        // u00 = e^{-i(phi+om)/2} c ; u01 = -e^{i(phi-om)/2} s
        // u10 = e^{-i(phi-om)/2} s ; u11 = e^{ i(phi+om)/2} c
        gm[t][0] =  c * chp;  gm[t][1] = -c * shp;
        gm[t][2] = -s * chm;  gm[t][3] = -s * shm;
        gm[t][4] =  s * chm;  gm[t][5] = -s * shm;
        gm[t][6] =  c * chp;  gm[t][7] =  c * shp;
    }
    __syncthreads();

    const float rn = 1.0f / sqrtf(snorm[0] + snorm[1] + snorm[2] + snorm[3]);
#pragma unroll
    for (int j = 0; j < 16; ++j) {
        re[t + j * 256] = x[j] * rn;
        im[t + j * 256] = 0.f;
    }
    __syncthreads();

    // ---- circuit ----
    for (int rep = 0; rep < 4; ++rep) {
        for (int l = 0; l < 4; ++l) {
            // 12 single-qubit Rot gates
            for (int q = 0; q < NQ; ++q) {
                const float* g = gm[l * NQ + q];
                const float u00r = g[0], u00i = g[1], u01r = g[2], u01i = g[3];
                const float u10r = g[4], u10i = g[5], u11r = g[6], u11i = g[7];
                const int bp = 11 - q;
                const int mask = (1 << bp) - 1;
#pragma unroll
                for (int j = 0; j < 8; ++j) {
                    const int p = t + j * 256;
                    const int i0 = ((p & ~mask) << 1) | (p & mask);
                    const int i1 = i0 | (1 << bp);
                    const float ar = re[i0], ai = im[i0];
                    const float br = re[i1], bi = im[i1];
                    re[i0] = u00r * ar - u00i * ai + u01r * br - u01i * bi;
                    im[i0] = u00r * ai + u00i * ar + u01r * bi + u01i * br;
                    re[i1] = u10r * ar - u10i * ai + u11r * br - u11i * bi;
                    im[i1] = u10r * ai + u10i * ar + u11r * bi + u11i * br;
                }
                __syncthreads();
            }
            // all 12 CNOTs of this layer as one permutation gather:
            // new[d] = old[T0(T1(...T11(d)))]   (each CNOT is self-inverse)
            const int r = l + 1;   // ranges: l % 11 + 1
            float tr[16], ti[16];
#pragma unroll
            for (int j = 0; j < 16; ++j) {
                int s = t + j * 256;
#pragma unroll
                for (int q = 11; q >= 0; --q) {
                    const int bc = 11 - q;
                    const int bt = 11 - ((q + r) % 12);
                    s ^= ((s >> bc) & 1) << bt;
                }
                tr[j] = re[s]; ti[j] = im[s];
            }
            __syncthreads();
#pragma unroll
            for (int j = 0; j < 16; ++j) {
                re[t + j * 256] = tr[j];
                im[t + j * 256] = ti[j];
            }
            __syncthreads();
        }
    }

    // ---- <Z_i> and final FC ----
    float zp[NQ] = {};
#pragma unroll
    for (int j = 0; j < 16; ++j) {
        const int s = t + j * 256;
        const float p = re[s] * re[s] + im[s] * im[s];
#pragma unroll
        for (int i = 0; i < NQ; ++i)
            zp[i] += ((s >> (11 - i)) & 1) ? -p : p;
    }
#pragma unroll
    for (int i = 0; i < NQ; ++i) {
        float v = zp[i];
#pragma unroll
        for (int off = 32; off; off >>= 1) v += __shfl_xor(v, off);
        if ((t & 63) == 0) redbuf[wave * NQ + i] = v;
    }
    __syncthreads();
    if (t < NQ)
        zs[t] = redbuf[t] + redbuf[NQ + t] + redbuf[2 * NQ + t] + redbuf[3 * NQ + t];
    __syncthreads();
    if (t < 10) {
        float o = bfc[t];
#pragma unroll
        for (int i = 0; i < NQ; ++i) o = fmaf(zs[i], Wfc[t * NQ + i], o);
        out[b * 10 + t] = o;
    }
}

extern "C" void kernel_launch(void* const* d_in, const int* in_sizes, int n_in,
                              void* d_out, int out_size, void* d_ws, size_t ws_size,
                              hipStream_t stream)
{
    const float* inputs = (const float*)d_in[0];   // 128 x 4096
    const float* W_pre  = (const float*)d_in[1];   // 4096 x 4096
    const float* b_pre  = (const float*)d_in[2];   // 4096
    const float* q_w    = (const float*)d_in[3];   // 4 x 12 x 3
    const float* W_fc   = (const float*)d_in[4];   // 10 x 12
    const float* b_fc   = (const float*)d_in[5];   // 10
    float* outp = (float*)d_out;                   // 128 x 10
    float* Xbuf = (float*)d_ws;                    // 128 x 4096 f32 = 2 MB

    dim3 g1(DIM / 64, BATCH / 64);
    gemm_gelu_kernel<<<g1, 256, 0, stream>>>(inputs, W_pre, b_pre, Xbuf);
    circuit_kernel<<<BATCH, 256, 0, stream>>>(Xbuf, q_w, W_fc, b_fc, outp);
}

// Round 2
// 146.030 us; speedup vs baseline: 2.6396x; 2.6396x over previous
//
#include <hip/hip_runtime.h>
#include <math.h>

#define DIM 4096
#define NQ 12
#define BATCH 128
#define BN 32
#define BK 64
#define ZSTR (128 * DIM)   // floats per split-k slab

typedef __attribute__((ext_vector_type(8))) short bf16x8;
typedef __attribute__((ext_vector_type(4))) float f32x4;

__device__ __forceinline__ unsigned short f2bf(float f) {
    union { float f; unsigned int u; } c; c.f = f;
    unsigned int u = c.u;
    unsigned int r = u + 0x7fffu + ((u >> 16) & 1u);   // RNE (finite inputs)
    return (unsigned short)(r >> 16);
}

// ---------------------------------------------------------------------------
// Kernel 1: split-K bf16 MFMA GEMM. psum[z][m][n] = A[m, kz] @ W[n, kz]^T
// BM=128 (full M), BN=32, BK=64. 256 threads = 4 waves, wave w owns M rows
// [32w, 32w+32). mfma_f32_16x16x32_bf16, f32 accumulate.
// ---------------------------------------------------------------------------
__global__ __launch_bounds__(256) void gemm_bf16_kernel(
    const float* __restrict__ A, const float* __restrict__ W,
    float* __restrict__ psum, int splitk)
{
    __shared__ unsigned short As[128][BK + 8];   // bf16 bits, +8 pad de-banks frag reads
    __shared__ unsigned short Bs[BN][BK + 8];

    const int t  = threadIdx.x;
    const int bn = blockIdx.x * BN;
    const int z  = blockIdx.y;
    const int krange = DIM / splitk;
    const int kstart = z * krange;
    const int w = t >> 6;
    const int l = t & 63;
    const int m0w = w * 32;

    f32x4 acc[2][2] = {};

    for (int k0 = kstart; k0 < kstart + krange; k0 += BK) {
        __syncthreads();   // previous iter's frag reads done
        // stage A: 128x64 f32 -> bf16 (8 float4 per thread)
#pragma unroll
        for (int i = 0; i < 8; ++i) {
            const int fid = t + i * 256;
            const int row = fid >> 4, c4 = (fid & 15) * 4;
            float4 v = *(const float4*)(A + (size_t)row * DIM + k0 + c4);
            union { unsigned short h[4]; uint2 u; } pk;
            pk.h[0] = f2bf(v.x); pk.h[1] = f2bf(v.y);
            pk.h[2] = f2bf(v.z); pk.h[3] = f2bf(v.w);
            *(uint2*)&As[row][c4] = pk.u;
        }
        // stage B: 32x64 (2 float4 per thread)
#pragma unroll
        for (int i = 0; i < 2; ++i) {
            const int fid = t + i * 256;
            const int row = fid >> 4, c4 = (fid & 15) * 4;
            float4 v = *(const float4*)(W + (size_t)(bn + row) * DIM + k0 + c4);
            union { unsigned short h[4]; uint2 u; } pk;
            pk.h[0] = f2bf(v.x); pk.h[1] = f2bf(v.y);
            pk.h[2] = f2bf(v.z); pk.h[3] = f2bf(v.w);
            *(uint2*)&Bs[row][c4] = pk.u;
        }
        __syncthreads();
#pragma unroll
        for (int kk = 0; kk < 2; ++kk) {
            const int kc = kk * 32 + (l >> 4) * 8;
            bf16x8 a0 = *(const bf16x8*)&As[m0w +      (l & 15)][kc];
            bf16x8 a1 = *(const bf16x8*)&As[m0w + 16 + (l & 15)][kc];
            bf16x8 b0 = *(const bf16x8*)&Bs[      (l & 15)][kc];
            bf16x8 b1 = *(const bf16x8*)&Bs[16 + (l & 15)][kc];
            acc[0][0] = __builtin_amdgcn_mfma_f32_16x16x32_bf16(a0, b0, acc[0][0], 0, 0, 0);
            acc[0][1] = __builtin_amdgcn_mfma_f32_16x16x32_bf16(a0, b1, acc[0][1], 0, 0, 0);
            acc[1][0] = __builtin_amdgcn_mfma_f32_16x16x32_bf16(a1, b0, acc[1][0], 0, 0, 0);
            acc[1][1] = __builtin_amdgcn_mfma_f32_16x16x32_bf16(a1, b1, acc[1][1], 0, 0, 0);
        }
    }
    // D layout: col = lane&15, row = (lane>>4)*4 + r   [learn_hip m89]
#pragma unroll
    for (int mf = 0; mf < 2; ++mf)
#pragma unroll
        for (int nf = 0; nf < 2; ++nf)
#pragma unroll
            for (int r = 0; r < 4; ++r) {
                const int m = m0w + mf * 16 + (l >> 4) * 4 + r;
                const int n = bn + nf * 16 + (l & 15);
                psum[(size_t)z * ZSTR + (size_t)m * DIM + n] = acc[mf][nf][r];
            }
}

// ---------------------------------------------------------------------------
// Kernel 2: reduce split-K partials + bias + exact GELU, in place into slab 0.
// ---------------------------------------------------------------------------
__global__ __launch_bounds__(256) void reduce_gelu_kernel(
    float* __restrict__ psum, const float* __restrict__ bias, int splitk)
{
    const size_t base = ((size_t)blockIdx.x * 256 + threadIdx.x) * 4;
    const int n = (int)(base & (DIM - 1));
    float4 s = *(float4*)(psum + base);
    for (int zz = 1; zz < splitk; ++zz) {
        float4 p = *(float4*)(psum + (size_t)zz * ZSTR + base);
        s.x += p.x; s.y += p.y; s.z += p.z; s.w += p.w;
    }
    float4 bb = *(const float4*)(bias + n);
    float h[4] = {s.x + bb.x, s.y + bb.y, s.z + bb.z, s.w + bb.w};
    float4 o;
    o.x = 0.5f * h[0] * (1.0f + erff(h[0] * 0.70710678118654752f));
    o.y = 0.5f * h[1] * (1.0f + erff(h[1] * 0.70710678118654752f));
    o.z = 0.5f * h[2] * (1.0f + erff(h[2] * 0.70710678118654752f));
    o.w = 0.5f * h[3] * (1.0f + erff(h[3] * 0.70710678118654752f));
    *(float4*)(psum + base) = o;
}

// ---------------------------------------------------------------------------
// Kernel 3: quantum circuit, register-resident state (8 amps/thread, 512 thr).
// Single-qubit gates on different qubits commute -> reorder each layer into
// 4 epochs of 3 thread-local-bit gates (register-only, no barriers). LDS only
// for the 4 re-permute transitions/layer (double-buffered, 1 barrier each).
// The 12-CNOT layer permutation is GF(2)-linear -> folded into the layer-end
// transition (s_src = F(t<<3) ^ fj[j], fj precomputed basis images).
// ---------------------------------------------------------------------------
__global__ __launch_bounds__(512) void circuit_kernel(
    const float* __restrict__ X, const float* __restrict__ qw,
    const float* __restrict__ Wfc, const float* __restrict__ bfc,
    float* __restrict__ out)
{
    __shared__ float2 sbuf[2][4096];   // 64 KB double-buffered state
    __shared__ float gm[48][8];
    __shared__ int   fj[4][8];         // CNOT-perm images of j (r = l+1)
    __shared__ float redw[8];
    __shared__ float zred[8][12];
    __shared__ float zbit[12];

    const int t = threadIdx.x;
    const int b = blockIdx.x;
    const int wv = t >> 6;

    // gate matrices: Rot(phi,theta,omega) entries (48 threads)
    if (t < 48) {
        const int base = t * 3;
        const float phi = qw[base + 0], th = qw[base + 1], om = qw[base + 2];
        float c, s, chp, shp, chm, shm;
        sincosf(0.5f * th, &s, &c);
        sincosf(0.5f * (phi + om), &shp, &chp);
        sincosf(0.5f * (phi - om), &shm, &chm);
        gm[t][0] =  c * chp;  gm[t][1] = -c * shp;
        gm[t][2] = -s * chm;  gm[t][3] = -s * shm;
        gm[t][4] =  s * chm;  gm[t][5] = -s * shm;
        gm[t][6] =  c * chp;  gm[t][7] =  c * shp;
    }
    // CNOT permutation basis images for j in [0,8): fj[r-1][j]
    if (t >= 64 && t < 96) {
        const int idx = t - 64;
        const int r = (idx >> 3) + 1;
        int s = idx & 7;
        for (int q = 11; q >= 0; --q) {
            const int bc = 11 - q, bt = 11 - ((q + r) % 12);
            s ^= ((s >> bc) & 1) << bt;
        }
        fj[idx >> 3][idx & 7] = s;
    }

    // load GELU'd row (epoch-0 mapping s = t*8+j is exactly coalesced)
    const float* xp = X + (size_t)b * DIM + t * 8;
    float4 v0 = *(const float4*)xp, v1 = *(const float4*)(xp + 4);
    float xr[8] = {v0.x, v0.y, v0.z, v0.w, v1.x, v1.y, v1.z, v1.w};
    float ss = 0.f;
#pragma unroll
    for (int j = 0; j < 8; ++j) ss = fmaf(xr[j], xr[j], ss);
#pragma unroll
    for (int off = 32; off; off >>= 1) ss += __shfl_xor(ss, off);
    if ((t & 63) == 0) redw[wv] = ss;
    __syncthreads();
    float tot = 0.f;
#pragma unroll
    for (int i = 0; i < 8; ++i) tot += redw[i];
    const float rn = 1.0f / sqrtf(tot);

    float sr[8], si[8];
#pragma unroll
    for (int j = 0; j < 8; ++j) { sr[j] = xr[j] * rn; si[j] = 0.f; }

    int tb = 0;
    for (int rep = 0; rep < 4; ++rep) {
        for (int l = 0; l < 4; ++l) {
            for (int e = 0; e < 4; ++e) {
                // ---- 3 register gates: bit positions 3e+lb  (q = 11-bp) ----
#pragma unroll
                for (int lb = 0; lb < 3; ++lb) {
                    const int bp = 3 * e + lb;
                    const float* g = gm[l * 12 + (11 - bp)];
                    const float u00r = g[0], u00i = g[1], u01r = g[2], u01i = g[3];
                    const float u10r = g[4], u10i = g[5], u11r = g[6], u11i = g[7];
#pragma unroll
                    for (int p = 0; p < 4; ++p) {
                        const int j0 = ((p >> lb) << (lb + 1)) | (p & ((1 << lb) - 1));
                        const int j1 = j0 | (1 << lb);
                        const float ar = sr[j0], ai = si[j0];
                        const float br = sr[j1], bi = si[j1];
                        sr[j0] = u00r * ar - u00i * ai + u01r * br - u01i * bi;
                        si[j0] = u00r * ai + u00i * ar + u01r * bi + u01i * br;
                        sr[j1] = u10r * ar - u10i * ai + u11r * br - u11i * bi;
                        si[j1] = u10r * ai + u10i * ar + u11r * bi + u11i * br;
                    }
                }
                // ---- transition: write epoch-e map, read next map ----
                const int sh = 3 * e;
#pragma unroll
                for (int j = 0; j < 8; ++j) {
                    const int s = ((t >> sh) << (sh + 3)) | (j << sh) | (t & ((1 << sh) - 1));
                    const int sl = s ^ ((s >> 4) & 15);   // bank swizzle
                    sbuf[tb][sl] = make_float2(sr[j], si[j]);
                }
                __syncthreads();
                if (e < 3) {
                    const int sh2 = sh + 3;
#pragma unroll
                    for (int j = 0; j < 8; ++j) {
                        const int s = ((t >> sh2) << (sh2 + 3)) | (j << sh2) | (t & ((1 << sh2) - 1));
                        const int sl = s ^ ((s >> 4) & 15);
                        float2 v = sbuf[tb][sl];
                        sr[j] = v.x; si[j] = v.y;
                    }
                } else {
                    // CNOT layer folded in: dest (t<<3)|j reads src F ^ fj[l][j]
                    const int r = l + 1;
                    int F = t << 3;
                    for (int q = 11; q >= 0; --q) {
                        const int bc = 11 - q, bt = 11 - ((q + r) % 12);
                        F ^= ((F >> bc) & 1) << bt;
                    }
#pragma unroll
                    for (int j = 0; j < 8; ++j) {
                        const int s = F ^ fj[l][j];
                        const int sl = s ^ ((s >> 4) & 15);
                        float2 v = sbuf[tb][sl];
                        sr[j] = v.x; si[j] = v.y;
                    }
                }
                tb ^= 1;
            }
        }
    }

    // ---- <Z_bp> partials; bits >=3 are thread-uniform ----
    float psumv = 0.f, z0 = 0.f, z1 = 0.f, z2 = 0.f;
#pragma unroll
    for (int j = 0; j < 8; ++j) {
        const float p = fmaf(sr[j], sr[j], si[j] * si[j]);
        psumv += p;
        z0 += (j & 1) ? -p : p;
        z1 += (j & 2) ? -p : p;
        z2 += (j & 4) ? -p : p;
    }
    float zp[12];
    zp[0] = z0; zp[1] = z1; zp[2] = z2;
#pragma unroll
    for (int bp = 3; bp < 12; ++bp)
        zp[bp] = ((t >> (bp - 3)) & 1) ? -psumv : psumv;
#pragma unroll
    for (int bp = 0; bp < 12; ++bp) {
        float v = zp[bp];
#pragma unroll
        for (int off = 32; off; off >>= 1) v += __shfl_xor(v, off);
        if ((t & 63) == 0) zred[wv][bp] = v;
    }
    __syncthreads();
    if (t < 12) {
        float v = 0.f;
#pragma unroll
        for (int w2 = 0; w2 < 8; ++w2) v += zred[w2][t];
        zbit[t] = v;
    }
    __syncthreads();
    if (t < 10) {
        float o = bfc[t];
#pragma unroll
        for (int q = 0; q < NQ; ++q) o = fmaf(zbit[11 - q], Wfc[t * NQ + q], o);
        out[b * 10 + t] = o;
    }
}

extern "C" void kernel_launch(void* const* d_in, const int* in_sizes, int n_in,
                              void* d_out, int out_size, void* d_ws, size_t ws_size,
                              hipStream_t stream)
{
    const float* inputs = (const float*)d_in[0];   // 128 x 4096
    const float* W_pre  = (const float*)d_in[1];   // 4096 x 4096
    const float* b_pre  = (const float*)d_in[2];   // 4096
    const float* q_w    = (const float*)d_in[3];   // 4 x 12 x 3
    const float* W_fc   = (const float*)d_in[4];   // 10 x 12
    const float* b_fc   = (const float*)d_in[5];   // 10
    float* outp = (float*)d_out;                   // 128 x 10
    float* psum = (float*)d_ws;                    // splitk x 128 x 4096 f32

    const size_t slab = (size_t)ZSTR * sizeof(float);   // 2 MB
    int splitk = 8;
    if (ws_size < 8 * slab) splitk = 4;
    if (ws_size < 4 * slab) splitk = 2;
    if (ws_size < 2 * slab) splitk = 1;

    dim3 g1(DIM / BN, splitk);
    gemm_bf16_kernel<<<g1, 256, 0, stream>>>(inputs, W_pre, psum, splitk);
    reduce_gelu_kernel<<<(128 * DIM / 4) / 256, 256, 0, stream>>>(psum, b_pre, splitk);
    circuit_kernel<<<BATCH, 512, 0, stream>>>(psum, q_w, W_fc, b_fc, outp);
}

// Round 3
// 131.834 us; speedup vs baseline: 2.9238x; 1.1077x over previous
//
#include <hip/hip_runtime.h>
#include <math.h>

#define DIM 4096
#define NQ 12
#define BATCH 128
#define BN 32
#define BK 64
#define ZSTR (128 * DIM)   // floats per split-k slab

typedef __attribute__((ext_vector_type(8))) short bf16x8;
typedef __attribute__((ext_vector_type(4))) float f32x4;

__device__ __forceinline__ unsigned short f2bf(float f) {
    union { float f; unsigned int u; } c; c.f = f;
    unsigned int u = c.u;
    unsigned int r = u + 0x7fffu + ((u >> 16) & 1u);   // RNE (finite inputs)
    return (unsigned short)(r >> 16);
}

// ---------------------------------------------------------------------------
// Kernel 1: split-K bf16 MFMA GEMM. psum[z][m][n] = A[m, kz] @ W[n, kz]^T
// ---------------------------------------------------------------------------
__global__ __launch_bounds__(256) void gemm_bf16_kernel(
    const float* __restrict__ A, const float* __restrict__ W,
    float* __restrict__ psum, int splitk)
{
    __shared__ unsigned short As[128][BK + 8];
    __shared__ unsigned short Bs[BN][BK + 8];

    const int t  = threadIdx.x;
    const int bn = blockIdx.x * BN;
    const int z  = blockIdx.y;
    const int krange = DIM / splitk;
    const int kstart = z * krange;
    const int w = t >> 6;
    const int l = t & 63;
    const int m0w = w * 32;

    f32x4 acc[2][2] = {};

    for (int k0 = kstart; k0 < kstart + krange; k0 += BK) {
        __syncthreads();
#pragma unroll
        for (int i = 0; i < 8; ++i) {
            const int fid = t + i * 256;
            const int row = fid >> 4, c4 = (fid & 15) * 4;
            float4 v = *(const float4*)(A + (size_t)row * DIM + k0 + c4);
            union { unsigned short h[4]; uint2 u; } pk;
            pk.h[0] = f2bf(v.x); pk.h[1] = f2bf(v.y);
            pk.h[2] = f2bf(v.z); pk.h[3] = f2bf(v.w);
            *(uint2*)&As[row][c4] = pk.u;
        }
#pragma unroll
        for (int i = 0; i < 2; ++i) {
            const int fid = t + i * 256;
            const int row = fid >> 4, c4 = (fid & 15) * 4;
            float4 v = *(const float4*)(W + (size_t)(bn + row) * DIM + k0 + c4);
            union { unsigned short h[4]; uint2 u; } pk;
            pk.h[0] = f2bf(v.x); pk.h[1] = f2bf(v.y);
            pk.h[2] = f2bf(v.z); pk.h[3] = f2bf(v.w);
            *(uint2*)&Bs[row][c4] = pk.u;
        }
        __syncthreads();
#pragma unroll
        for (int kk = 0; kk < 2; ++kk) {
            const int kc = kk * 32 + (l >> 4) * 8;
            bf16x8 a0 = *(const bf16x8*)&As[m0w +      (l & 15)][kc];
            bf16x8 a1 = *(const bf16x8*)&As[m0w + 16 + (l & 15)][kc];
            bf16x8 b0 = *(const bf16x8*)&Bs[      (l & 15)][kc];
            bf16x8 b1 = *(const bf16x8*)&Bs[16 + (l & 15)][kc];
            acc[0][0] = __builtin_amdgcn_mfma_f32_16x16x32_bf16(a0, b0, acc[0][0], 0, 0, 0);
            acc[0][1] = __builtin_amdgcn_mfma_f32_16x16x32_bf16(a0, b1, acc[0][1], 0, 0, 0);
            acc[1][0] = __builtin_amdgcn_mfma_f32_16x16x32_bf16(a1, b0, acc[1][0], 0, 0, 0);
            acc[1][1] = __builtin_amdgcn_mfma_f32_16x16x32_bf16(a1, b1, acc[1][1], 0, 0, 0);
        }
    }
#pragma unroll
    for (int mf = 0; mf < 2; ++mf)
#pragma unroll
        for (int nf = 0; nf < 2; ++nf)
#pragma unroll
            for (int r = 0; r < 4; ++r) {
                const int m = m0w + mf * 16 + (l >> 4) * 4 + r;
                const int n = bn + nf * 16 + (l & 15);
                psum[(size_t)z * ZSTR + (size_t)m * DIM + n] = acc[mf][nf][r];
            }
}

// ---------------------------------------------------------------------------
// Kernel 2: reduce split-K partials + bias + exact GELU, in place into slab 0.
// ---------------------------------------------------------------------------
__global__ __launch_bounds__(256) void reduce_gelu_kernel(
    float* __restrict__ psum, const float* __restrict__ bias, int splitk)
{
    const size_t base = ((size_t)blockIdx.x * 256 + threadIdx.x) * 4;
    const int n = (int)(base & (DIM - 1));
    float4 s = *(float4*)(psum + base);
    for (int zz = 1; zz < splitk; ++zz) {
        float4 p = *(float4*)(psum + (size_t)zz * ZSTR + base);
        s.x += p.x; s.y += p.y; s.z += p.z; s.w += p.w;
    }
    float4 bb = *(const float4*)(bias + n);
    float h[4] = {s.x + bb.x, s.y + bb.y, s.z + bb.z, s.w + bb.w};
    float4 o;
    o.x = 0.5f * h[0] * (1.0f + erff(h[0] * 0.70710678118654752f));
    o.y = 0.5f * h[1] * (1.0f + erff(h[1] * 0.70710678118654752f));
    o.z = 0.5f * h[2] * (1.0f + erff(h[2] * 0.70710678118654752f));
    o.w = 0.5f * h[3] * (1.0f + erff(h[3] * 0.70710678118654752f));
    *(float4*)(psum + base) = o;
}

// ---------------------------------------------------------------------------
// Kernel 3: quantum circuit. 1024 threads, 4 amps/thread (16 waves = 4/SIMD).
// State index bits: [1:0]=register j, [7:2]=lane, [11:8]=wave.
// Per layer: 2 register gates (bits 0-1) + 6 __shfl_xor gates (bits 2-7,
// no LDS/no barrier) + 3 LDS transitions for the 4 wave-bit gates:
//   T1: swap bits 0-1 <-> 8-9   (gates q=3,2 in registers)
//   T2: swap bits 8-9 <-> 10-11 (gates q=1,0 in registers)
//   T3: restore identity mapping with the 12-CNOT permutation folded in.
// Slots swizzled x^((x>>4)&15): every transition = uniform 4 lanes/bank-pair
// (wave64 b64 hardware minimum).
// ---------------------------------------------------------------------------
__global__ __launch_bounds__(1024) void circuit_kernel(
    const float* __restrict__ X, const float* __restrict__ qw,
    const float* __restrict__ Wfc, const float* __restrict__ bfc,
    float* __restrict__ out)
{
    __shared__ float2 sbuf[2][4096];   // 64 KB double-buffered state
    __shared__ float gm[48][8];
    __shared__ int   pj[4][4];         // Pinv_l(j) for j-bit images
    __shared__ float redw[16];
    __shared__ float zred[16][12];
    __shared__ float zbit[12];

    const int t = threadIdx.x;
    const int b = blockIdx.x;
    const int wv  = t >> 6;
    const int l6  = t & 63;
    const int w01 = wv & 3;
    const int w23 = wv >> 2;
    const int lbits = l6 << 2;

    if (t < 48) {
        const int base = t * 3;
        const float phi = qw[base + 0], th = qw[base + 1], om = qw[base + 2];
        float c, s, chp, shp, chm, shm;
        sincosf(0.5f * th, &s, &c);
        sincosf(0.5f * (phi + om), &shp, &chp);
        sincosf(0.5f * (phi - om), &shm, &chm);
        gm[t][0] =  c * chp;  gm[t][1] = -c * shp;   // u00
        gm[t][2] = -s * chm;  gm[t][3] = -s * shm;   // u01
        gm[t][4] =  s * chm;  gm[t][5] = -s * shm;   // u10
        gm[t][6] =  c * chp;  gm[t][7] =  c * shp;   // u11
    }
    if (t < 16) {
        const int ll = t >> 2, r = ll + 1;
        int u = t & 3;
        for (int q = 11; q >= 0; --q) {
            const int bc = 11 - q, bt2 = 11 - ((q + r) % 12);
            u ^= ((u >> bc) & 1) << bt2;
        }
        pj[ll][t & 3] = u;
    }
    // per-thread CNOT-perm base images (registers, one per layer)
    int fb[4];
#pragma unroll
    for (int ll = 0; ll < 4; ++ll) {
        const int r = ll + 1;
        int u = t << 2;
        for (int q = 11; q >= 0; --q) {
            const int bc = 11 - q, bt2 = 11 - ((q + r) % 12);
            u ^= ((u >> bc) & 1) << bt2;
        }
        fb[ll] = u;
    }

    // load GELU'd row (identity map s = t*4+j is exactly this float4)
    float4 v = *(const float4*)(X + (size_t)b * DIM + t * 4);
    float sr[4] = {v.x, v.y, v.z, v.w};
    float si[4] = {0.f, 0.f, 0.f, 0.f};
    float ss = v.x * v.x + v.y * v.y + v.z * v.z + v.w * v.w;
#pragma unroll
    for (int off = 32; off; off >>= 1) ss += __shfl_xor(ss, off);
    if (l6 == 0) redw[wv] = ss;
    __syncthreads();
    float tot = 0.f;
#pragma unroll
    for (int i = 0; i < 16; ++i) tot += redw[i];
    const float rn = 1.0f / sqrtf(tot);
#pragma unroll
    for (int j = 0; j < 4; ++j) sr[j] *= rn;

#define SW(x) ((x) ^ (((x) >> 4) & 15))

    auto reg_gate = [&](int lb, const float* g) {
        const float u00r = g[0], u00i = g[1], u01r = g[2], u01i = g[3];
        const float u10r = g[4], u10i = g[5], u11r = g[6], u11i = g[7];
#pragma unroll
        for (int p = 0; p < 2; ++p) {
            const int j0 = (lb == 0) ? (p << 1) : p;
            const int j1 = j0 | (1 << lb);
            const float ar = sr[j0], ai = si[j0];
            const float br = sr[j1], bi = si[j1];
            sr[j0] = u00r * ar - u00i * ai + u01r * br - u01i * bi;
            si[j0] = u00r * ai + u00i * ar + u01r * bi + u01i * br;
            sr[j1] = u10r * ar - u10i * ai + u11r * br - u11i * bi;
            si[j1] = u10r * ai + u10i * ar + u11r * bi + u11i * br;
        }
    };

    int tb = 0;
    for (int rep = 0; rep < 4; ++rep) {
        for (int l = 0; l < 4; ++l) {
            const float* gL = &gm[l * 12][0];
            // ---- epoch 1 (identity map): reg gates bits 0,1 (q=11,10) ----
            reg_gate(0, gL + 11 * 8);
            reg_gate(1, gL + 10 * 8);
            // ---- shfl gates bits 2..7 (q = 9..4), mask = 1<<(bp-2) ----
#pragma unroll
            for (int bp = 2; bp <= 7; ++bp) {
                const float* g = gL + (11 - bp) * 8;
                const int m = 1 << (bp - 2);
                const int bsel = (l6 >> (bp - 2)) & 1;
                const float car = bsel ? g[6] : g[0], cai = bsel ? g[7] : g[1];
                const float cbr = bsel ? g[4] : g[2], cbi = bsel ? g[5] : g[3];
#pragma unroll
                for (int j = 0; j < 4; ++j) {
                    const float pr = __shfl_xor(sr[j], m);
                    const float pi = __shfl_xor(si[j], m);
                    const float nr = car * sr[j] - cai * si[j] + cbr * pr - cbi * pi;
                    const float ni = car * si[j] + cai * sr[j] + cbr * pi + cbi * pr;
                    sr[j] = nr; si[j] = ni;
                }
            }
            // ---- T1: write idx0, read idx1 (swap bits 0-1 <-> 8-9) ----
#pragma unroll
            for (int j = 0; j < 4; ++j) {
                const int idx = j | lbits | (w01 << 8) | (w23 << 10);
                sbuf[tb][SW(idx)] = make_float2(sr[j], si[j]);
            }
            __syncthreads();
#pragma unroll
            for (int j = 0; j < 4; ++j) {
                const int idx = w01 | lbits | (j << 8) | (w23 << 10);
                float2 a = sbuf[tb][SW(idx)];
                sr[j] = a.x; si[j] = a.y;
            }
            tb ^= 1;
            // ---- epoch 2: reg gates on orig bits 8,9 (q=3,2) ----
            reg_gate(0, gL + 3 * 8);
            reg_gate(1, gL + 2 * 8);
            // ---- T2: write idx1, read idx2 (swap bits 8-9 <-> 10-11) ----
#pragma unroll
            for (int j = 0; j < 4; ++j) {
                const int idx = w01 | lbits | (j << 8) | (w23 << 10);
                sbuf[tb][SW(idx)] = make_float2(sr[j], si[j]);
            }
            __syncthreads();
#pragma unroll
            for (int j = 0; j < 4; ++j) {
                const int idx = w01 | lbits | (w23 << 8) | (j << 10);
                float2 a = sbuf[tb][SW(idx)];
                sr[j] = a.x; si[j] = a.y;
            }
            tb ^= 1;
            // ---- epoch 3: reg gates on orig bits 10,11 (q=1,0) ----
            reg_gate(0, gL + 1 * 8);
            reg_gate(1, gL + 0 * 8);
            // ---- T3: write idx2, read Pinv(idx0) (restore + CNOT fold) ----
#pragma unroll
            for (int j = 0; j < 4; ++j) {
                const int idx = w01 | lbits | (w23 << 8) | (j << 10);
                sbuf[tb][SW(idx)] = make_float2(sr[j], si[j]);
            }
            __syncthreads();
#pragma unroll
            for (int j = 0; j < 4; ++j) {
                const int idx = fb[l] ^ pj[l][j];
                float2 a = sbuf[tb][SW(idx)];
                sr[j] = a.x; si[j] = a.y;
            }
            tb ^= 1;
        }
    }

    // ---- <Z_bp> partials; bits >=2 are thread-uniform ----
    float p0 = sr[0] * sr[0] + si[0] * si[0];
    float p1 = sr[1] * sr[1] + si[1] * si[1];
    float p2 = sr[2] * sr[2] + si[2] * si[2];
    float p3 = sr[3] * sr[3] + si[3] * si[3];
    const float psumv = p0 + p1 + p2 + p3;
    float zp[12];
    zp[0] = p0 - p1 + p2 - p3;
    zp[1] = p0 + p1 - p2 - p3;
#pragma unroll
    for (int bp = 2; bp < 12; ++bp)
        zp[bp] = ((t >> (bp - 2)) & 1) ? -psumv : psumv;
#pragma unroll
    for (int bp = 0; bp < 12; ++bp) {
        float vv = zp[bp];
#pragma unroll
        for (int off = 32; off; off >>= 1) vv += __shfl_xor(vv, off);
        if (l6 == 0) zred[wv][bp] = vv;
    }
    __syncthreads();
    if (t < 12) {
        float vv = 0.f;
#pragma unroll
        for (int w2 = 0; w2 < 16; ++w2) vv += zred[w2][t];
        zbit[t] = vv;
    }
    __syncthreads();
    if (t < 10) {
        float o = bfc[t];
#pragma unroll
        for (int q = 0; q < NQ; ++q) o = fmaf(zbit[11 - q], Wfc[t * NQ + q], o);
        out[b * 10 + t] = o;
    }
#undef SW
}

extern "C" void kernel_launch(void* const* d_in, const int* in_sizes, int n_in,
                              void* d_out, int out_size, void* d_ws, size_t ws_size,
                              hipStream_t stream)
{
    const float* inputs = (const float*)d_in[0];   // 128 x 4096
    const float* W_pre  = (const float*)d_in[1];   // 4096 x 4096
    const float* b_pre  = (const float*)d_in[2];   // 4096
    const float* q_w    = (const float*)d_in[3];   // 4 x 12 x 3
    const float* W_fc   = (const float*)d_in[4];   // 10 x 12
    const float* b_fc   = (const float*)d_in[5];   // 10
    float* outp = (float*)d_out;                   // 128 x 10
    float* psum = (float*)d_ws;                    // splitk x 128 x 4096 f32

    const size_t slab = (size_t)ZSTR * sizeof(float);   // 2 MB
    int splitk = 8;
    if (ws_size < 8 * slab) splitk = 4;
    if (ws_size < 4 * slab) splitk = 2;
    if (ws_size < 2 * slab) splitk = 1;

    dim3 g1(DIM / BN, splitk);
    gemm_bf16_kernel<<<g1, 256, 0, stream>>>(inputs, W_pre, psum, splitk);
    reduce_gelu_kernel<<<(128 * DIM / 4) / 256, 256, 0, stream>>>(psum, b_pre, splitk);
    circuit_kernel<<<BATCH, 1024, 0, stream>>>(psum, q_w, W_fc, b_fc, outp);
}

// Round 4
// 98.285 us; speedup vs baseline: 3.9219x; 1.3413x over previous
//
#include <hip/hip_runtime.h>
#include <math.h>

#define DIM 4096
#define NQ 12
#define BATCH 128
#define BN 32
#define BK 64
#define ZSTR (128 * DIM)   // floats per split-k slab

typedef __attribute__((ext_vector_type(8))) short bf16x8;
typedef __attribute__((ext_vector_type(4))) float f32x4;
typedef unsigned int uint2v __attribute__((ext_vector_type(2)));

__device__ __forceinline__ unsigned short f2bf(float f) {
    union { float f; unsigned int u; } c; c.f = f;
    unsigned int u = c.u;
    unsigned int r = u + 0x7fffu + ((u >> 16) & 1u);   // RNE (finite inputs)
    return (unsigned short)(r >> 16);
}

// ---------------------------------------------------------------------------
// Kernel 1: split-K bf16 MFMA GEMM with register prefetch double-buffering.
// psum[z][m][n] = A[m, kz] @ W[n, kz]^T ; BM=128, BN=32, BK=64, 4 waves.
// ---------------------------------------------------------------------------
__global__ __launch_bounds__(256) void gemm_bf16_kernel(
    const float* __restrict__ A, const float* __restrict__ W,
    float* __restrict__ psum, int splitk)
{
    __shared__ unsigned short As[128][BK + 8];
    __shared__ unsigned short Bs[BN][BK + 8];

    const int t  = threadIdx.x;
    const int bn = blockIdx.x * BN;
    const int z  = blockIdx.y;
    const int krange = DIM / splitk;
    const int kstart = z * krange;
    const int kend = kstart + krange;
    const int w = t >> 6;
    const int l = t & 63;
    const int m0w = w * 32;

    f32x4 acc[2][2] = {};
    float4 pa[8], pb[2];

    auto load_tiles = [&](int k0) {
#pragma unroll
        for (int i = 0; i < 8; ++i) {
            const int fid = t + i * 256;
            pa[i] = *(const float4*)(A + (size_t)(fid >> 4) * DIM + k0 + (fid & 15) * 4);
        }
#pragma unroll
        for (int i = 0; i < 2; ++i) {
            const int fid = t + i * 256;
            pb[i] = *(const float4*)(W + (size_t)(bn + (fid >> 4)) * DIM + k0 + (fid & 15) * 4);
        }
    };

    load_tiles(kstart);
    for (int k0 = kstart; k0 < kend; k0 += BK) {
        __syncthreads();   // previous iteration's LDS reads done
#pragma unroll
        for (int i = 0; i < 8; ++i) {
            const int fid = t + i * 256;
            const int row = fid >> 4, c4 = (fid & 15) * 4;
            union { unsigned short h[4]; uint2 u; } pk;
            pk.h[0] = f2bf(pa[i].x); pk.h[1] = f2bf(pa[i].y);
            pk.h[2] = f2bf(pa[i].z); pk.h[3] = f2bf(pa[i].w);
            *(uint2*)&As[row][c4] = pk.u;
        }
#pragma unroll
        for (int i = 0; i < 2; ++i) {
            const int fid = t + i * 256;
            const int row = fid >> 4, c4 = (fid & 15) * 4;
            union { unsigned short h[4]; uint2 u; } pk;
            pk.h[0] = f2bf(pb[i].x); pk.h[1] = f2bf(pb[i].y);
            pk.h[2] = f2bf(pb[i].z); pk.h[3] = f2bf(pb[i].w);
            *(uint2*)&Bs[row][c4] = pk.u;
        }
        // prefetch next tile into registers (latency hides under MFMA phase)
        const int kn = (k0 + BK < kend) ? (k0 + BK) : k0;
        load_tiles(kn);
        __syncthreads();
#pragma unroll
        for (int kk = 0; kk < 2; ++kk) {
            const int kc = kk * 32 + (l >> 4) * 8;
            bf16x8 a0 = *(const bf16x8*)&As[m0w +      (l & 15)][kc];
            bf16x8 a1 = *(const bf16x8*)&As[m0w + 16 + (l & 15)][kc];
            bf16x8 b0 = *(const bf16x8*)&Bs[      (l & 15)][kc];
            bf16x8 b1 = *(const bf16x8*)&Bs[16 + (l & 15)][kc];
            acc[0][0] = __builtin_amdgcn_mfma_f32_16x16x32_bf16(a0, b0, acc[0][0], 0, 0, 0);
            acc[0][1] = __builtin_amdgcn_mfma_f32_16x16x32_bf16(a0, b1, acc[0][1], 0, 0, 0);
            acc[1][0] = __builtin_amdgcn_mfma_f32_16x16x32_bf16(a1, b0, acc[1][0], 0, 0, 0);
            acc[1][1] = __builtin_amdgcn_mfma_f32_16x16x32_bf16(a1, b1, acc[1][1], 0, 0, 0);
        }
    }
#pragma unroll
    for (int mf = 0; mf < 2; ++mf)
#pragma unroll
        for (int nf = 0; nf < 2; ++nf)
#pragma unroll
            for (int r = 0; r < 4; ++r) {
                const int m = m0w + mf * 16 + (l >> 4) * 4 + r;
                const int n = bn + nf * 16 + (l & 15);
                psum[(size_t)z * ZSTR + (size_t)m * DIM + n] = acc[mf][nf][r];
            }
}

// ---------------------------------------------------------------------------
// lane-exchange primitives (all off the DS pipe except nothing!)
// ---------------------------------------------------------------------------
template<int CTRL>
__device__ __forceinline__ float fdpp(float v) {
    return __int_as_float(__builtin_amdgcn_update_dpp(
        0, __float_as_int(v), CTRL, 0xF, 0xF, false));
}
// partner via permlane{16,32}_swap; exact & order-independent: a^b^own
__device__ __forceinline__ float pl16_partner(float v) {
#if __has_builtin(__builtin_amdgcn_permlane16_swap)
    uint2v r = __builtin_amdgcn_permlane16_swap(__float_as_uint(v), __float_as_uint(v), false, false);
    return __uint_as_float(r.x ^ r.y ^ __float_as_uint(v));
#else
    float a = v, b = v;
    asm volatile("v_permlane16_swap_b32 %0, %1" : "+v"(a), "+v"(b));
    return __uint_as_float(__float_as_uint(a) ^ __float_as_uint(b) ^ __float_as_uint(v));
#endif
}
__device__ __forceinline__ float pl32_partner(float v) {
#if __has_builtin(__builtin_amdgcn_permlane32_swap)
    uint2v r = __builtin_amdgcn_permlane32_swap(__float_as_uint(v), __float_as_uint(v), false, false);
    return __uint_as_float(r.x ^ r.y ^ __float_as_uint(v));
#else
    float a = v, b = v;
    asm volatile("v_permlane32_swap_b32 %0, %1" : "+v"(a), "+v"(b));
    return __uint_as_float(__float_as_uint(a) ^ __float_as_uint(b) ^ __float_as_uint(v));
#endif
}

// ---------------------------------------------------------------------------
// Kernel 2: fused reduce+GELU+norm + quantum circuit. 1024 threads, 4 amps.
// State bits: [1:0]=reg j, [7:2]=lane, [11:8]=wave.
// Lane-bit gates: bit2=quad_perm xor1, bit3=quad xor2, bit4=HM*Q3(xor4),
// bit5=M*HM(xor8), bit6=permlane16, bit7=permlane32 -> all VALU-pipe.
// Wave-bit gates via 3 swizzled LDS transitions/layer (4 b64 w + 4 b64 r).
// CNOT layer folded into T3's read permutation (GF(2)-linear).
// ---------------------------------------------------------------------------
__global__ __launch_bounds__(1024) void circuit_kernel(
    const float* __restrict__ psum, int splitk, const float* __restrict__ bias,
    const float* __restrict__ qw, const float* __restrict__ Wfc,
    const float* __restrict__ bfc, float* __restrict__ out)
{
    __shared__ float2 sbuf[2][4096];   // 64 KB double-buffered state
    __shared__ float4 gm4[48][2];      // gate matrices, 32B/gate
    __shared__ int   sspj[4][4];       // SW(sigma(pj)) images
    __shared__ float redw[16];
    __shared__ float zred[16][12];
    __shared__ float zbit[12];

    const int t = threadIdx.x;
    const int b = blockIdx.x;
    const int wv = t >> 6;
    const int l6 = t & 63;
    const int w01 = wv & 3;
    const int w23 = wv >> 2;

    // gate matrices Rot(phi,theta,omega)
    if (t < 48) {
        const int base = t * 3;
        const float phi = qw[base + 0], th = qw[base + 1], om = qw[base + 2];
        float c, s, chp, shp, chm, shm;
        sincosf(0.5f * th, &s, &c);
        sincosf(0.5f * (phi + om), &shp, &chp);
        sincosf(0.5f * (phi - om), &shm, &chm);
        float* g = (float*)&gm4[t][0];
        g[0] =  c * chp;  g[1] = -c * shp;   // u00
        g[2] = -s * chm;  g[3] = -s * shm;   // u01
        g[4] =  s * chm;  g[5] = -s * shm;   // u10
        g[6] =  c * chp;  g[7] =  c * shp;   // u11
    }
#define SWZ(x) ((x) ^ (((x) >> 4) & 15))
#define SIG3(x) (((((x) >> 8) & 3) << 10) | (((x) & 3) << 8) | ((((x) >> 2) & 63) << 2) | (((x) >> 10) & 3))
    // CNOT perm j-images, sigma3+SW transformed
    if (t < 16) {
        const int ll = t >> 2, r = ll + 1;
        int u = t & 3;
        for (int q = 11; q >= 0; --q) {
            const int bc = 11 - q, bt2 = 11 - ((q + r) % 12);
            u ^= ((u >> bc) & 1) << bt2;
        }
        int s3 = SIG3(u);
        sspj[ll][t & 3] = SWZ(s3);
    }
    // per-thread CNOT base images, sigma3+SW transformed
    int ssfb[4];
#pragma unroll
    for (int ll = 0; ll < 4; ++ll) {
        const int r = ll + 1;
        int u = t << 2;
        for (int q = 11; q >= 0; --q) {
            const int bc = 11 - q, bt2 = 11 - ((q + r) % 12);
            u ^= ((u >> bc) & 1) << bt2;
        }
        int s3 = SIG3(u);
        ssfb[ll] = SWZ(s3);
    }
    // swizzled transition bases (SW is GF(2)-linear; j-parts pass through)
    const int b1w = SWZ((w23 << 8) | (l6 << 2) | w01);              // T1 write ^ (j<<10)
    const int b1r = SWZ((w01 << 10) | (w23 << 8) | (l6 << 2));      // T1 read  ^ j
    const int b2w = SWZ((w01 << 8) | (l6 << 2) | w23);              // T2 write ^ (j<<10)
    const int b2r = SWZ((w23 << 10) | (w01 << 8) | (l6 << 2));      // T2 read ^ j; also T3 write ^ j

    // ---- fused split-K reduce + bias + exact GELU + norm ----
    float a0 = 0.f, a1 = 0.f, a2 = 0.f, a3 = 0.f;
    for (int z = 0; z < splitk; ++z) {
        const float4 p = *(const float4*)(psum + (size_t)z * ZSTR + (size_t)b * DIM + t * 4);
        a0 += p.x; a1 += p.y; a2 += p.z; a3 += p.w;
    }
    {
        const float4 bb = *(const float4*)(bias + t * 4);
        a0 += bb.x; a1 += bb.y; a2 += bb.z; a3 += bb.w;
    }
    float xr[4];
    xr[0] = 0.5f * a0 * (1.0f + erff(a0 * 0.70710678118654752f));
    xr[1] = 0.5f * a1 * (1.0f + erff(a1 * 0.70710678118654752f));
    xr[2] = 0.5f * a2 * (1.0f + erff(a2 * 0.70710678118654752f));
    xr[3] = 0.5f * a3 * (1.0f + erff(a3 * 0.70710678118654752f));
    float ss = xr[0]*xr[0] + xr[1]*xr[1] + xr[2]*xr[2] + xr[3]*xr[3];
#pragma unroll
    for (int off = 32; off; off >>= 1) ss += __shfl_xor(ss, off);
    if (l6 == 0) redw[wv] = ss;
    __syncthreads();
    float tot = 0.f;
#pragma unroll
    for (int i = 0; i < 16; ++i) tot += redw[i];
    const float rn = 1.0f / sqrtf(tot);

    float sr[4], si[4];
#pragma unroll
    for (int j = 0; j < 4; ++j) { sr[j] = xr[j] * rn; si[j] = 0.f; }

    auto reg_gate = [&](int lb, float4 g0, float4 g1) {
#pragma unroll
        for (int p = 0; p < 2; ++p) {
            const int j0 = (lb == 0) ? (p << 1) : p;
            const int j1 = j0 | (1 << lb);
            const float ar = sr[j0], ai = si[j0];
            const float br = sr[j1], bi = si[j1];
            sr[j0] = g0.x * ar - g0.y * ai + g0.z * br - g0.w * bi;
            si[j0] = g0.x * ai + g0.y * ar + g0.z * bi + g0.w * br;
            sr[j1] = g1.x * ar - g1.y * ai + g1.z * br - g1.w * bi;
            si[j1] = g1.x * ai + g1.y * ar + g1.z * bi + g1.w * br;
        }
    };
    auto lane_gate = [&](int lanebit, auto&& partner, float4 g0, float4 g1) {
        const int bsel = (l6 >> lanebit) & 1;
        const float cAr = bsel ? g1.z : g0.x, cAi = bsel ? g1.w : g0.y;  // own coef
        const float cBr = bsel ? g1.x : g0.z, cBi = bsel ? g1.y : g0.w;  // partner coef
#pragma unroll
        for (int j = 0; j < 4; ++j) {
            const float pr = partner(sr[j]), pi = partner(si[j]);
            const float nr = cAr * sr[j] - cAi * si[j] + cBr * pr - cBi * pi;
            const float ni = cAr * si[j] + cAi * sr[j] + cBr * pi + cBi * pr;
            sr[j] = nr; si[j] = ni;
        }
    };

    int tb = 0;
    for (int rep = 0; rep < 4; ++rep) {
#pragma unroll
        for (int l = 0; l < 4; ++l) {
            const int gb = l * 12;
            // ---- epoch A (identity map): bits 0-7 ----
            reg_gate(0, gm4[gb + 11][0], gm4[gb + 11][1]);
            reg_gate(1, gm4[gb + 10][0], gm4[gb + 10][1]);
            lane_gate(0, [](float v) { return fdpp<0xB1>(v); },               gm4[gb + 9][0], gm4[gb + 9][1]);
            lane_gate(1, [](float v) { return fdpp<0x4E>(v); },               gm4[gb + 8][0], gm4[gb + 8][1]);
            lane_gate(2, [](float v) { return fdpp<0x1B>(fdpp<0x141>(v)); },  gm4[gb + 7][0], gm4[gb + 7][1]);
            lane_gate(3, [](float v) { return fdpp<0x141>(fdpp<0x140>(v)); }, gm4[gb + 6][0], gm4[gb + 6][1]);
            lane_gate(4, [](float v) { return pl16_partner(v); },             gm4[gb + 5][0], gm4[gb + 5][1]);
            lane_gate(5, [](float v) { return pl32_partner(v); },             gm4[gb + 4][0], gm4[gb + 4][1]);
            // ---- T1: j <-> bits 8,9 ----
#pragma unroll
            for (int j = 0; j < 4; ++j) sbuf[tb][b1w ^ (j << 10)] = make_float2(sr[j], si[j]);
            __syncthreads();
#pragma unroll
            for (int j = 0; j < 4; ++j) { float2 a = sbuf[tb][b1r ^ j]; sr[j] = a.x; si[j] = a.y; }
            tb ^= 1;
            // ---- epoch B: bits 8,9 (q=3,2) ----
            reg_gate(0, gm4[gb + 3][0], gm4[gb + 3][1]);
            reg_gate(1, gm4[gb + 2][0], gm4[gb + 2][1]);
            // ---- T2: j <-> bits 10,11 ----
#pragma unroll
            for (int j = 0; j < 4; ++j) sbuf[tb][b2w ^ (j << 10)] = make_float2(sr[j], si[j]);
            __syncthreads();
#pragma unroll
            for (int j = 0; j < 4; ++j) { float2 a = sbuf[tb][b2r ^ j]; sr[j] = a.x; si[j] = a.y; }
            tb ^= 1;
            // ---- epoch C: bits 10,11 (q=1,0) ----
            reg_gate(0, gm4[gb + 1][0], gm4[gb + 1][1]);
            reg_gate(1, gm4[gb + 0][0], gm4[gb + 0][1]);
            // ---- T3: restore identity + fold CNOT layer ----
#pragma unroll
            for (int j = 0; j < 4; ++j) sbuf[tb][b2r ^ j] = make_float2(sr[j], si[j]);
            __syncthreads();
#pragma unroll
            for (int j = 0; j < 4; ++j) { float2 a = sbuf[tb][ssfb[l] ^ sspj[l][j]]; sr[j] = a.x; si[j] = a.y; }
            tb ^= 1;
        }
    }

    // ---- <Z_bp> partials; bits >=2 are thread-uniform ----
    float p0 = sr[0]*sr[0] + si[0]*si[0];
    float p1 = sr[1]*sr[1] + si[1]*si[1];
    float p2 = sr[2]*sr[2] + si[2]*si[2];
    float p3 = sr[3]*sr[3] + si[3]*si[3];
    const float psumv = p0 + p1 + p2 + p3;
    float zp[12];
    zp[0] = p0 - p1 + p2 - p3;
    zp[1] = p0 + p1 - p2 - p3;
#pragma unroll
    for (int bp = 2; bp < 12; ++bp)
        zp[bp] = ((t >> (bp - 2)) & 1) ? -psumv : psumv;
#pragma unroll
    for (int bp = 0; bp < 12; ++bp) {
        float vv = zp[bp];
#pragma unroll
        for (int off = 32; off; off >>= 1) vv += __shfl_xor(vv, off);
        if (l6 == 0) zred[wv][bp] = vv;
    }
    __syncthreads();
    if (t < 12) {
        float vv = 0.f;
#pragma unroll
        for (int w2 = 0; w2 < 16; ++w2) vv += zred[w2][t];
        zbit[t] = vv;
    }
    __syncthreads();
    if (t < 10) {
        float o = bfc[t];
#pragma unroll
        for (int q = 0; q < NQ; ++q) o = fmaf(zbit[11 - q], Wfc[t * NQ + q], o);
        out[b * 10 + t] = o;
    }
#undef SWZ
#undef SIG3
}

extern "C" void kernel_launch(void* const* d_in, const int* in_sizes, int n_in,
                              void* d_out, int out_size, void* d_ws, size_t ws_size,
                              hipStream_t stream)
{
    const float* inputs = (const float*)d_in[0];   // 128 x 4096
    const float* W_pre  = (const float*)d_in[1];   // 4096 x 4096
    const float* b_pre  = (const float*)d_in[2];   // 4096
    const float* q_w    = (const float*)d_in[3];   // 4 x 12 x 3
    const float* W_fc   = (const float*)d_in[4];   // 10 x 12
    const float* b_fc   = (const float*)d_in[5];   // 10
    float* outp = (float*)d_out;                   // 128 x 10
    float* psum = (float*)d_ws;                    // splitk x 128 x 4096 f32

    const size_t slab = (size_t)ZSTR * sizeof(float);   // 2 MB
    int splitk = 4;
    if (ws_size < 4 * slab) splitk = 2;
    if (ws_size < 2 * slab) splitk = 1;

    dim3 g1(DIM / BN, splitk);
    gemm_bf16_kernel<<<g1, 256, 0, stream>>>(inputs, W_pre, psum, splitk);
    circuit_kernel<<<BATCH, 1024, 0, stream>>>(psum, splitk, b_pre, q_w, W_fc, b_fc, outp);
}